// Round 7
// baseline (1737.537 us; speedup 1.0000x reference)
//
#include <hip/hip_runtime.h>
#include <hip/hip_bf16.h>

// GRU-GAN generator, MI355X. Round 16 — R14 base (best: 1393us rocprof) +
// X2s eliminated (out-proj applies 2nd leaky in-register from Xs, in its
// leg1 slack) + leg1 MFMA issue order accR->accN1->accZ (starts the eU
// critical chain 2 MFMA-latencies earlier; eZ overlaps the chain tail).
// R15 (8-wave consolidation) regressed +46us: lengthened dir=0 leg2 ->
// leg critical-path length is directly visible in total time. Reverted.
// B=512, H=64, S=2048, F=32. 32 blocks x 768 threads (12 waves, 3/SIMD).
//   waves 0-7 : gates (dir=w>>2, cb=w&3). Leg1: x-read, 6 gi MFMA
//               (scale-folded), merged-rcp elementwise, packed h write
//               [prio 1]. Leg2: 6 gh MFMA (carried regs) [prio 0].
//   waves 8-11: latent (+ out-proj on 8-9). Leg1 (waves 8-9, slack):
//               Xs[HB] read, in-reg lk (2nd leaky), 2 MFMA, pre-scaled
//               sigmoid, un-drained f32x4 store of y(T-1) [prio 0].
//               Leg2: h(t+1) read both dirs, 2+2 MFMA, lk, Xs write [prio 1].
// Barriers: gates plain __syncthreads; latent path raw s_barrier (b1) /
// lgkm-only drain (b2) so y-stores never block.
// Scale folding (R14): r/z rows * -log2e, n rows * -2log2e, Wout * -log2e.
// Numerics: per-accumulator MFMA association order unchanged vs R14;
// out-proj input lk(bf16(lk(la))) == R11's validated path -> absmax stable.

#define NBATCH 512
#define NH 64
#define NS 2048
#define NF 32
#define MROW 16
#define LDH 72    // padded LDS row stride (shorts): 144 B

typedef short s16x8 __attribute__((ext_vector_type(8)));
typedef float f32x4 __attribute__((ext_vector_type(4)));

#define MFMA(a, b, c) __builtin_amdgcn_mfma_f32_16x16x32_bf16((a), (b), (c), 0, 0, 0)

#define NLOG2E  (-1.4426950408889634f)   // -log2(e)
#define N2LOG2E (-2.8853900817779268f)   // -2*log2(e)

__device__ __forceinline__ void bar_nodrain() {
    asm volatile("s_barrier" ::: "memory");
}

__device__ __forceinline__ void bar_lgkm() {
    asm volatile("s_waitcnt lgkmcnt(0)\n\ts_barrier" ::: "memory");
}

__device__ __forceinline__ short f2bf(float f) {
    return (short)((__float_as_uint(f) + 0x8000u) >> 16);
}

__device__ __forceinline__ f32x4 v_exp2(f32x4 a) {
    f32x4 r;
#pragma unroll
    for (int i = 0; i < 4; ++i) r[i] = __builtin_amdgcn_exp2f(a[i]);
    return r;
}

__device__ __forceinline__ f32x4 v_rcp(f32x4 a) {
    f32x4 r;
#pragma unroll
    for (int i = 0; i < 4; ++i) r[i] = __builtin_amdgcn_rcpf(a[i]);
    return r;
}

__device__ __forceinline__ f32x4 v_lk(f32x4 a) {
    f32x4 b = a * 0.01f;
    f32x4 r;
#pragma unroll
    for (int i = 0; i < 4; ++i) r[i] = fmaxf(a[i], b[i]);
    return r;
}

// sigmoid of pre-scaled input: a = -log2e * z  ->  1/(1+2^a)
__device__ __forceinline__ f32x4 v_sigm_pre(f32x4 a) {
    return v_rcp(v_exp2(a) + 1.0f);
}

__device__ __forceinline__ int2 pk4bf(f32x4 v) {
    union { __hip_bfloat162 b; int i; } lo, hi;
    float2 a; a.x = v[0]; a.y = v[1];
    float2 b; b.x = v[2]; b.y = v[3];
    lo.b = __float22bfloat162_rn(a);
    hi.b = __float22bfloat162_rn(b);
    int2 r; r.x = lo.i; r.y = hi.i;
    return r;
}

// apply leaky-ReLU elementwise to a bf16 fragment (out-proj's 2nd leaky)
__device__ __forceinline__ s16x8 lk_frag(s16x8 v) {
    f32x4 lo, hi;
#pragma unroll
    for (int i = 0; i < 4; ++i) {
        lo[i] = __uint_as_float(((unsigned)(unsigned short)v[i]) << 16);
        hi[i] = __uint_as_float(((unsigned)(unsigned short)v[i + 4]) << 16);
    }
    union { struct { int2 a, b; } p; s16x8 s; } u;
    u.p.a = pk4bf(v_lk(lo));
    u.p.b = pk4bf(v_lk(hi));
    return u.s;
}

__device__ __forceinline__ s16x8 bfragW(const float* __restrict__ W, int ldk,
                                        int row, int kf, int quad, float scale) {
    const float* p = W + (size_t)row * ldk + kf * 32 + quad * 8;
    s16x8 r;
#pragma unroll
    for (int i = 0; i < 8; ++i) r[i] = f2bf(p[i] * scale);
    return r;
}

__device__ __forceinline__ f32x4 bias4s(const float* __restrict__ p, float scale) {
    const float4 v = *(const float4*)p;
    f32x4 r = {v.x * scale, v.y * scale, v.z * scale, v.w * scale};
    return r;
}

__global__ __launch_bounds__(768)
void grugan_kernel(const float* __restrict__ noise,
                   const float* __restrict__ Wihf, const float* __restrict__ Whhf,
                   const float* __restrict__ bihf, const float* __restrict__ bhhf,
                   const float* __restrict__ Wihb, const float* __restrict__ Whhb,
                   const float* __restrict__ bihb, const float* __restrict__ bhhb,
                   const float* __restrict__ Wlat, const float* __restrict__ blat,
                   const float* __restrict__ Wout, const float* __restrict__ bout,
                   float* __restrict__ out)
{
    __shared__ __align__(16) short Xs[2][MROW][LDH];
    __shared__ __align__(16) short Hs[2][2][MROW][LDH];

    const int tid  = threadIdx.x;
    const int wave = tid >> 6;
    const int lane = tid & 63;
    const int n    = lane & 15;   // batch row within tile
    const int quad = lane >> 4;
    const int row0 = blockIdx.x * MROW;

    // zero x(0); init h(0) (gate waves hold hreg; both dirs covered)
    for (int idx = tid; idx < MROW * LDH; idx += 768) (&Xs[0][0][0])[idx] = 0;
    f32x4 hreg = {0.f, 0.f, 0.f, 0.f};
    const int gdir = wave >> 2;             // valid for waves 0-7
    const int gjq  = (wave & 3) * 16 + quad * 4;
    if (wave < 8) {
        const float4 nz = *(const float4*)&noise[(size_t)(row0 + n) * NH + gjq];
        hreg[0] = nz.x; hreg[1] = nz.y; hreg[2] = nz.z; hreg[3] = nz.w;
        *(int2*)&Hs[0][gdir][n][gjq] = pk4bf(hreg);
    }
    __syncthreads();

    if (wave < 8) {
        // ======================= GATE WAVES =======================
        const int dir  = gdir;
        const int cb   = wave & 3;
        const int jrow = cb * 16 + n;
        const int jq   = gjq;
        const float* Wih = dir ? Wihb : Wihf;
        const float* Whh = dir ? Whhb : Whhf;
        const float* bih = dir ? bihb : bihf;
        const float* bhh = dir ? bhhb : bhhf;

        // r/z rows scaled by -log2e; n rows by -2log2e (scale folding)
        s16x8 wir0 = bfragW(Wih, NH,   0 + jrow, 0, quad, NLOG2E);
        s16x8 wir1 = bfragW(Wih, NH,   0 + jrow, 1, quad, NLOG2E);
        s16x8 wiz0 = bfragW(Wih, NH,  64 + jrow, 0, quad, NLOG2E);
        s16x8 wiz1 = bfragW(Wih, NH,  64 + jrow, 1, quad, NLOG2E);
        s16x8 win0 = bfragW(Wih, NH, 128 + jrow, 0, quad, N2LOG2E);
        s16x8 win1 = bfragW(Wih, NH, 128 + jrow, 1, quad, N2LOG2E);
        s16x8 whr0 = bfragW(Whh, NH,   0 + jrow, 0, quad, NLOG2E);
        s16x8 whr1 = bfragW(Whh, NH,   0 + jrow, 1, quad, NLOG2E);
        s16x8 whz0 = bfragW(Whh, NH,  64 + jrow, 0, quad, NLOG2E);
        s16x8 whz1 = bfragW(Whh, NH,  64 + jrow, 1, quad, NLOG2E);
        s16x8 whn0 = bfragW(Whh, NH, 128 + jrow, 0, quad, N2LOG2E);
        s16x8 whn1 = bfragW(Whh, NH, 128 + jrow, 1, quad, N2LOG2E);
        f32x4 initR, initZ;
        {
            f32x4 a = bias4s(&bih[jq], NLOG2E), b = bias4s(&bhh[jq], NLOG2E);
            initR = a + b;
            f32x4 c = bias4s(&bih[64 + jq], NLOG2E), d = bias4s(&bhh[64 + jq], NLOG2E);
            initZ = c + d;
        }
        const f32x4 initN1 = bias4s(&bih[128 + jq], N2LOG2E);
        const f32x4 initN2 = bias4s(&bhh[128 + jq], N2LOG2E);

        // prologue: gh accumulators for t=0 from h(0)
        f32x4 accR, accZ, accN2;
        {
            s16x8 ha0 = *(const s16x8*)&Hs[0][dir][n][quad * 8];
            s16x8 ha1 = *(const s16x8*)&Hs[0][dir][n][32 + quad * 8];
            accR  = MFMA(whr0, ha0, initR);  accR  = MFMA(whr1, ha1, accR);
            accZ  = MFMA(whz0, ha0, initZ);  accZ  = MFMA(whz1, ha1, accZ);
            accN2 = MFMA(whn0, ha0, initN2); accN2 = MFMA(whn1, ha1, accN2);
        }

#define GSTEP(HB) do {                                                          \
        __builtin_amdgcn_s_setprio(1);  /* leg1: gates are the straggler */     \
        s16x8 xa0 = *(const s16x8*)&Xs[HB][n][quad * 8];                        \
        s16x8 xa1 = *(const s16x8*)&Xs[HB][n][32 + quad * 8];                   \
        /* issue order: accR first (heads the eU critical chain), then   */     \
        /* accN1, accZ last (eZ only needed at the chain tail).          */     \
        accR = MFMA(wir0, xa0, accR);   accR = MFMA(wir1, xa1, accR);           \
        f32x4 accN1 = MFMA(win0, xa0, initN1);                                  \
        accN1 = MFMA(win1, xa1, accN1);                                         \
        accZ = MFMA(wiz0, xa0, accZ);   accZ = MFMA(wiz1, xa1, accZ);           \
        f32x4 eR = v_exp2(accR);                                                \
        f32x4 rr = v_rcp(eR + 1.0f);                                            \
        f32x4 eU = v_exp2(accN1 + rr * accN2);                                  \
        f32x4 eZ = v_exp2(accZ);                                                \
        f32x4 numer = (eZ + hreg) + eU * (hreg - eZ);                           \
        f32x4 denom = (eU + 1.0f) * (eZ + 1.0f);                                \
        hreg = numer * v_rcp(denom);                                            \
        *(int2*)&Hs[(HB) ^ 1][dir][n][jq] = pk4bf(hreg);                        \
        __builtin_amdgcn_s_setprio(0);  /* leg2: yield to latent waves */       \
        __syncthreads();  /* b1: H(t+1) visible */                              \
        {                                                                       \
            s16x8 ha0 = *(const s16x8*)&Hs[(HB) ^ 1][dir][n][quad * 8];         \
            s16x8 ha1 = *(const s16x8*)&Hs[(HB) ^ 1][dir][n][32 + quad * 8];    \
            accR  = MFMA(whr0, ha0, initR);  accR  = MFMA(whr1, ha1, accR);     \
            accZ  = MFMA(whz0, ha0, initZ);  accZ  = MFMA(whz1, ha1, accZ);     \
            accN2 = MFMA(whn0, ha0, initN2); accN2 = MFMA(whn1, ha1, accN2);    \
        }                                                                       \
        __syncthreads();  /* b2: x(t+1) visible */                              \
    } while (0)

        for (int t = 0; t < NS; t += 2) {
            GSTEP(0);
            GSTEP(1);
        }
#undef GSTEP
    } else {
        // =============== LATENT WAVES (+ fused OUT-PROJ on lt<2) ===============
        const int lt = wave & 3;
        const int nq = lt * 16 + quad * 4;
        s16x8 wl0 = bfragW(Wlat, 2 * NH, lt * 16 + n, 0, quad, 1.0f);
        s16x8 wl1 = bfragW(Wlat, 2 * NH, lt * 16 + n, 1, quad, 1.0f);
        s16x8 wl2 = bfragW(Wlat, 2 * NH, lt * 16 + n, 2, quad, 1.0f);
        s16x8 wl3 = bfragW(Wlat, 2 * NH, lt * 16 + n, 3, quad, 1.0f);
        const f32x4 initL = bias4s(&blat[lt * 16 + quad * 4], 1.0f);

        // out-proj state (waves 8-9 only: f-tile f0 = lt*16), pre-scaled -log2e
        s16x8 wo0 = {}, wo1 = {};
        f32x4 initO = {0.f, 0.f, 0.f, 0.f};
        float* orow = nullptr;
        if (lt < 2) {
            const int f0 = lt * 16;
            wo0   = bfragW(Wout, NH, f0 + n, 0, quad, NLOG2E);
            wo1   = bfragW(Wout, NH, f0 + n, 1, quad, NLOG2E);
            initO = bias4s(&bout[f0 + quad * 4], NLOG2E);
            orow  = out + (size_t)(row0 + n) * (NS * NF) + f0 + quad * 4;
        }
        const f32x4 zero4 = {0.f, 0.f, 0.f, 0.f};

#define LOSTEP(HB, T) do {                                                      \
        if (lt < 2 && (T) > 0) {                                                \
            /* leg1 (prio 0 — slack): out-proj of y(T-1) from lk(Xs[HB]); */    \
            /* store never drained (raw barriers keep vmcnt outstanding). */    \
            s16x8 p0 = lk_frag(*(const s16x8*)&Xs[HB][n][quad * 8]);            \
            s16x8 p1 = lk_frag(*(const s16x8*)&Xs[HB][n][32 + quad * 8]);       \
            f32x4 po = MFMA(wo0, p0, initO);                                    \
            po = MFMA(wo1, p1, po);                                             \
            *(f32x4*)(orow + (size_t)((T) - 1) * NF) = v_sigm_pre(po);          \
        }                                                                       \
        bar_nodrain();    /* b1: H(T+1) visible (we have nothing pending) */    \
        __builtin_amdgcn_s_setprio(1);  /* leg2: latent is the straggler */     \
        s16x8 fa0 = *(const s16x8*)&Hs[(HB) ^ 1][0][n][quad * 8];               \
        s16x8 fa1 = *(const s16x8*)&Hs[(HB) ^ 1][0][n][32 + quad * 8];          \
        s16x8 ba0 = *(const s16x8*)&Hs[(HB) ^ 1][1][n][quad * 8];               \
        s16x8 ba1 = *(const s16x8*)&Hs[(HB) ^ 1][1][n][32 + quad * 8];          \
        f32x4 lac1 = MFMA(wl0, fa0, initL);                                     \
        lac1 = MFMA(wl1, fa1, lac1);                                            \
        f32x4 lac2 = MFMA(wl2, ba0, zero4);                                     \
        lac2 = MFMA(wl3, ba1, lac2);                                            \
        f32x4 la = lac1 + lac2;                                                 \
        *(int2*)&Xs[(HB) ^ 1][n][nq] = pk4bf(v_lk(la));                         \
        __builtin_amdgcn_s_setprio(0);  /* leg1: yield to gate waves */         \
        bar_lgkm();       /* b2: x(T+1) visible (lgkm drain only) */            \
    } while (0)

        for (int t = 0; t < NS; t += 2) {
            LOSTEP(0, t);
            LOSTEP(1, t + 1);
        }
#undef LOSTEP

        // epilogue: y(NS-1) from lk(Xs[0]) (= lk2(x(NS)), written at T=NS-1,
        // visible via the loop's final bar_lgkm)
        if (lt < 2) {
            s16x8 p0 = lk_frag(*(const s16x8*)&Xs[0][n][quad * 8]);
            s16x8 p1 = lk_frag(*(const s16x8*)&Xs[0][n][32 + quad * 8]);
            f32x4 po = MFMA(wo0, p0, initO);
            po = MFMA(wo1, p1, po);
            *(f32x4*)(orow + (size_t)(NS - 1) * NF) = v_sigm_pre(po);
        }
    }
}

extern "C" void kernel_launch(void* const* d_in, const int* in_sizes, int n_in,
                              void* d_out, int out_size, void* d_ws, size_t ws_size,
                              hipStream_t stream) {
    const float* noise = (const float*)d_in[0];
    const float* Wihf  = (const float*)d_in[1];
    const float* Whhf  = (const float*)d_in[2];
    const float* bihf  = (const float*)d_in[3];
    const float* bhhf  = (const float*)d_in[4];
    const float* Wihb  = (const float*)d_in[5];
    const float* Whhb  = (const float*)d_in[6];
    const float* bihb  = (const float*)d_in[7];
    const float* bhhb  = (const float*)d_in[8];
    const float* Wlat  = (const float*)d_in[9];
    const float* blat  = (const float*)d_in[10];
    const float* Wout  = (const float*)d_in[11];
    const float* bout  = (const float*)d_in[12];

    grugan_kernel<<<dim3(NBATCH / MROW), dim3(768), 0, stream>>>(
        noise, Wihf, Whhf, bihf, bhhf, Wihb, Whhb, bihb, bhhb,
        Wlat, blat, Wout, bout, (float*)d_out);
}

// Round 8
// 1487.469 us; speedup vs baseline: 1.1681x; 1.1681x over previous
//
#include <hip/hip_runtime.h>
#include <hip/hip_bf16.h>

// GRU-GAN generator, MI355X. Round 17 — exact R14 revert (best: 1393us) +
// fma-folded denom (one fewer dependent op before the final rcp).
// R16 (X2s-elim + MFMA reorder) regressed to 1622us: lk_frag in the prio-0
// out-proj leg1 got issue-starved ~3x by prio-1 gate waves and became the
// b1 straggler. Lesson: prio-0 slack legs must stay SHORT; X2s (written in
// latent leg2, prio 1) keeps out-proj trivial. Restored.
// B=512, H=64, S=2048, F=32. 32 blocks x 768 threads (12 waves, 3/SIMD).
//   waves 0-7 : gates (dir=w>>2, cb=w&3). Leg1: x-read, 6 gi MFMA
//               (scale-folded), merged-rcp elementwise, packed h write
//               [prio 1]. Leg2: 6 gh MFMA (carried regs) [prio 0].
//   waves 8-11: latent (+ out-proj on 8-9). Leg1 (waves 8-9, slack):
//               X2s read, 2 MFMA, pre-scaled sigmoid, un-drained f32x4
//               store of y(T-1) [prio 0].
//               Leg2: h(t+1) read both dirs, 2+2 MFMA, lk/lk2, Xs+X2s
//               writes [prio 1].
// Barriers: gates plain __syncthreads; latent path raw s_barrier (b1) /
// lgkm-only drain (b2) so y-stores never block.
// Scale folding: r/z rows * -log2e, n rows * -2log2e, Wout * -log2e.
// Issued-work model (active CUs = 32/256, counters 8x diluted): ~820cy/SIMD/
// step issued vs 1630cy measured -> ~50% packed; trans pipe (40 instr x 8cy)
// is the largest unsharable term and is at the exact-GRU minimum.

#define NBATCH 512
#define NH 64
#define NS 2048
#define NF 32
#define MROW 16
#define LDH 72    // padded LDS row stride (shorts): 144 B

typedef short s16x8 __attribute__((ext_vector_type(8)));
typedef float f32x4 __attribute__((ext_vector_type(4)));

#define MFMA(a, b, c) __builtin_amdgcn_mfma_f32_16x16x32_bf16((a), (b), (c), 0, 0, 0)

#define NLOG2E  (-1.4426950408889634f)   // -log2(e)
#define N2LOG2E (-2.8853900817779268f)   // -2*log2(e)

__device__ __forceinline__ void bar_nodrain() {
    asm volatile("s_barrier" ::: "memory");
}

__device__ __forceinline__ void bar_lgkm() {
    asm volatile("s_waitcnt lgkmcnt(0)\n\ts_barrier" ::: "memory");
}

__device__ __forceinline__ short f2bf(float f) {
    return (short)((__float_as_uint(f) + 0x8000u) >> 16);
}

__device__ __forceinline__ f32x4 v_exp2(f32x4 a) {
    f32x4 r;
#pragma unroll
    for (int i = 0; i < 4; ++i) r[i] = __builtin_amdgcn_exp2f(a[i]);
    return r;
}

__device__ __forceinline__ f32x4 v_rcp(f32x4 a) {
    f32x4 r;
#pragma unroll
    for (int i = 0; i < 4; ++i) r[i] = __builtin_amdgcn_rcpf(a[i]);
    return r;
}

__device__ __forceinline__ f32x4 v_lk(f32x4 a) {
    f32x4 b = a * 0.01f;
    f32x4 r;
#pragma unroll
    for (int i = 0; i < 4; ++i) r[i] = fmaxf(a[i], b[i]);
    return r;
}

// lk(lk(x)) = max(x, 1e-4*x) in one stage
__device__ __forceinline__ f32x4 v_lk2(f32x4 a) {
    f32x4 b = a * 1e-4f;
    f32x4 r;
#pragma unroll
    for (int i = 0; i < 4; ++i) r[i] = fmaxf(a[i], b[i]);
    return r;
}

// sigmoid of pre-scaled input: a = -log2e * z  ->  1/(1+2^a)
__device__ __forceinline__ f32x4 v_sigm_pre(f32x4 a) {
    return v_rcp(v_exp2(a) + 1.0f);
}

__device__ __forceinline__ int2 pk4bf(f32x4 v) {
    union { __hip_bfloat162 b; int i; } lo, hi;
    float2 a; a.x = v[0]; a.y = v[1];
    float2 b; b.x = v[2]; b.y = v[3];
    lo.b = __float22bfloat162_rn(a);
    hi.b = __float22bfloat162_rn(b);
    int2 r; r.x = lo.i; r.y = hi.i;
    return r;
}

__device__ __forceinline__ s16x8 bfragW(const float* __restrict__ W, int ldk,
                                        int row, int kf, int quad, float scale) {
    const float* p = W + (size_t)row * ldk + kf * 32 + quad * 8;
    s16x8 r;
#pragma unroll
    for (int i = 0; i < 8; ++i) r[i] = f2bf(p[i] * scale);
    return r;
}

__device__ __forceinline__ f32x4 bias4s(const float* __restrict__ p, float scale) {
    const float4 v = *(const float4*)p;
    f32x4 r = {v.x * scale, v.y * scale, v.z * scale, v.w * scale};
    return r;
}

__global__ __launch_bounds__(768)
void grugan_kernel(const float* __restrict__ noise,
                   const float* __restrict__ Wihf, const float* __restrict__ Whhf,
                   const float* __restrict__ bihf, const float* __restrict__ bhhf,
                   const float* __restrict__ Wihb, const float* __restrict__ Whhb,
                   const float* __restrict__ bihb, const float* __restrict__ bhhb,
                   const float* __restrict__ Wlat, const float* __restrict__ blat,
                   const float* __restrict__ Wout, const float* __restrict__ bout,
                   float* __restrict__ out)
{
    __shared__ __align__(16) short Xs[2][MROW][LDH];
    __shared__ __align__(16) short X2s[2][MROW][LDH];
    __shared__ __align__(16) short Hs[2][2][MROW][LDH];

    const int tid  = threadIdx.x;
    const int wave = tid >> 6;
    const int lane = tid & 63;
    const int n    = lane & 15;   // batch row within tile
    const int quad = lane >> 4;
    const int row0 = blockIdx.x * MROW;

    // zero x(0); init h(0) (gate waves hold hreg; both dirs covered)
    for (int idx = tid; idx < MROW * LDH; idx += 768) (&Xs[0][0][0])[idx] = 0;
    f32x4 hreg = {0.f, 0.f, 0.f, 0.f};
    const int gdir = wave >> 2;             // valid for waves 0-7
    const int gjq  = (wave & 3) * 16 + quad * 4;
    if (wave < 8) {
        const float4 nz = *(const float4*)&noise[(size_t)(row0 + n) * NH + gjq];
        hreg[0] = nz.x; hreg[1] = nz.y; hreg[2] = nz.z; hreg[3] = nz.w;
        *(int2*)&Hs[0][gdir][n][gjq] = pk4bf(hreg);
    }
    __syncthreads();

    if (wave < 8) {
        // ======================= GATE WAVES =======================
        const int dir  = gdir;
        const int cb   = wave & 3;
        const int jrow = cb * 16 + n;
        const int jq   = gjq;
        const float* Wih = dir ? Wihb : Wihf;
        const float* Whh = dir ? Whhb : Whhf;
        const float* bih = dir ? bihb : bihf;
        const float* bhh = dir ? bhhb : bhhf;

        // r/z rows scaled by -log2e; n rows by -2log2e (scale folding)
        s16x8 wir0 = bfragW(Wih, NH,   0 + jrow, 0, quad, NLOG2E);
        s16x8 wir1 = bfragW(Wih, NH,   0 + jrow, 1, quad, NLOG2E);
        s16x8 wiz0 = bfragW(Wih, NH,  64 + jrow, 0, quad, NLOG2E);
        s16x8 wiz1 = bfragW(Wih, NH,  64 + jrow, 1, quad, NLOG2E);
        s16x8 win0 = bfragW(Wih, NH, 128 + jrow, 0, quad, N2LOG2E);
        s16x8 win1 = bfragW(Wih, NH, 128 + jrow, 1, quad, N2LOG2E);
        s16x8 whr0 = bfragW(Whh, NH,   0 + jrow, 0, quad, NLOG2E);
        s16x8 whr1 = bfragW(Whh, NH,   0 + jrow, 1, quad, NLOG2E);
        s16x8 whz0 = bfragW(Whh, NH,  64 + jrow, 0, quad, NLOG2E);
        s16x8 whz1 = bfragW(Whh, NH,  64 + jrow, 1, quad, NLOG2E);
        s16x8 whn0 = bfragW(Whh, NH, 128 + jrow, 0, quad, N2LOG2E);
        s16x8 whn1 = bfragW(Whh, NH, 128 + jrow, 1, quad, N2LOG2E);
        f32x4 initR, initZ;
        {
            f32x4 a = bias4s(&bih[jq], NLOG2E), b = bias4s(&bhh[jq], NLOG2E);
            initR = a + b;
            f32x4 c = bias4s(&bih[64 + jq], NLOG2E), d = bias4s(&bhh[64 + jq], NLOG2E);
            initZ = c + d;
        }
        const f32x4 initN1 = bias4s(&bih[128 + jq], N2LOG2E);
        const f32x4 initN2 = bias4s(&bhh[128 + jq], N2LOG2E);

        // prologue: gh accumulators for t=0 from h(0)
        f32x4 accR, accZ, accN2;
        {
            s16x8 ha0 = *(const s16x8*)&Hs[0][dir][n][quad * 8];
            s16x8 ha1 = *(const s16x8*)&Hs[0][dir][n][32 + quad * 8];
            accR  = MFMA(whr0, ha0, initR);  accR  = MFMA(whr1, ha1, accR);
            accZ  = MFMA(whz0, ha0, initZ);  accZ  = MFMA(whz1, ha1, accZ);
            accN2 = MFMA(whn0, ha0, initN2); accN2 = MFMA(whn1, ha1, accN2);
        }

#define GSTEP(HB) do {                                                          \
        __builtin_amdgcn_s_setprio(1);  /* leg1: gates are the straggler */     \
        s16x8 xa0 = *(const s16x8*)&Xs[HB][n][quad * 8];                        \
        s16x8 xa1 = *(const s16x8*)&Xs[HB][n][32 + quad * 8];                   \
        accR = MFMA(wir0, xa0, accR);   accR = MFMA(wir1, xa1, accR);           \
        accZ = MFMA(wiz0, xa0, accZ);   accZ = MFMA(wiz1, xa1, accZ);           \
        f32x4 accN1 = MFMA(win0, xa0, initN1);                                  \
        accN1 = MFMA(win1, xa1, accN1);                                         \
        /* scale-folded: accR/accZ = -log2e*(gi+gh), accN* = -2log2e*(...) */   \
        f32x4 eR = v_exp2(accR);                                                \
        f32x4 rr = v_rcp(eR + 1.0f);                                            \
        f32x4 eU = v_exp2(accN1 + rr * accN2);                                  \
        f32x4 eZ = v_exp2(accZ);                                                \
        f32x4 numer = (eZ + hreg) + eU * (hreg - eZ);                           \
        f32x4 tz    = eZ + 1.0f;                                                \
        f32x4 denom = eU * tz + tz;   /* fma((eU+1)(eZ+1)): -1 chain op */      \
        hreg = numer * v_rcp(denom);                                            \
        *(int2*)&Hs[(HB) ^ 1][dir][n][jq] = pk4bf(hreg);                        \
        __builtin_amdgcn_s_setprio(0);  /* leg2: yield to latent waves */       \
        __syncthreads();  /* b1: H(t+1) visible */                              \
        {                                                                       \
            s16x8 ha0 = *(const s16x8*)&Hs[(HB) ^ 1][dir][n][quad * 8];         \
            s16x8 ha1 = *(const s16x8*)&Hs[(HB) ^ 1][dir][n][32 + quad * 8];    \
            accR  = MFMA(whr0, ha0, initR);  accR  = MFMA(whr1, ha1, accR);     \
            accZ  = MFMA(whz0, ha0, initZ);  accZ  = MFMA(whz1, ha1, accZ);     \
            accN2 = MFMA(whn0, ha0, initN2); accN2 = MFMA(whn1, ha1, accN2);    \
        }                                                                       \
        __syncthreads();  /* b2: x(t+1) visible */                              \
    } while (0)

        for (int t = 0; t < NS; t += 2) {
            GSTEP(0);
            GSTEP(1);
        }
#undef GSTEP
    } else {
        // =============== LATENT WAVES (+ fused OUT-PROJ on lt<2) ===============
        const int lt = wave & 3;
        const int nq = lt * 16 + quad * 4;
        s16x8 wl0 = bfragW(Wlat, 2 * NH, lt * 16 + n, 0, quad, 1.0f);
        s16x8 wl1 = bfragW(Wlat, 2 * NH, lt * 16 + n, 1, quad, 1.0f);
        s16x8 wl2 = bfragW(Wlat, 2 * NH, lt * 16 + n, 2, quad, 1.0f);
        s16x8 wl3 = bfragW(Wlat, 2 * NH, lt * 16 + n, 3, quad, 1.0f);
        const f32x4 initL = bias4s(&blat[lt * 16 + quad * 4], 1.0f);

        // out-proj state (waves 8-9 only: f-tile f0 = lt*16), pre-scaled -log2e
        s16x8 wo0 = {}, wo1 = {};
        f32x4 initO = {0.f, 0.f, 0.f, 0.f};
        float* orow = nullptr;
        if (lt < 2) {
            const int f0 = lt * 16;
            wo0   = bfragW(Wout, NH, f0 + n, 0, quad, NLOG2E);
            wo1   = bfragW(Wout, NH, f0 + n, 1, quad, NLOG2E);
            initO = bias4s(&bout[f0 + quad * 4], NLOG2E);
            orow  = out + (size_t)(row0 + n) * (NS * NF) + f0 + quad * 4;
        }
        const f32x4 zero4 = {0.f, 0.f, 0.f, 0.f};

#define LOSTEP(HB, T) do {                                                      \
        if (lt < 2 && (T) > 0) {                                                \
            /* leg1 (prio 0 — slack, must stay SHORT): out-proj of y(T-1) */    \
            /* from X2s[HB]; store never drained (raw barriers).          */    \
            s16x8 p0 = *(const s16x8*)&X2s[HB][n][quad * 8];                    \
            s16x8 p1 = *(const s16x8*)&X2s[HB][n][32 + quad * 8];               \
            f32x4 po = MFMA(wo0, p0, initO);                                    \
            po = MFMA(wo1, p1, po);                                             \
            *(f32x4*)(orow + (size_t)((T) - 1) * NF) = v_sigm_pre(po);          \
        }                                                                       \
        bar_nodrain();    /* b1: H(T+1) visible (we have nothing pending) */    \
        __builtin_amdgcn_s_setprio(1);  /* leg2: latent is the straggler */     \
        s16x8 fa0 = *(const s16x8*)&Hs[(HB) ^ 1][0][n][quad * 8];               \
        s16x8 fa1 = *(const s16x8*)&Hs[(HB) ^ 1][0][n][32 + quad * 8];          \
        s16x8 ba0 = *(const s16x8*)&Hs[(HB) ^ 1][1][n][quad * 8];               \
        s16x8 ba1 = *(const s16x8*)&Hs[(HB) ^ 1][1][n][32 + quad * 8];          \
        f32x4 lac1 = MFMA(wl0, fa0, initL);                                     \
        lac1 = MFMA(wl1, fa1, lac1);                                            \
        f32x4 lac2 = MFMA(wl2, ba0, zero4);                                     \
        lac2 = MFMA(wl3, ba1, lac2);                                            \
        f32x4 la = lac1 + lac2;                                                 \
        *(int2*)&Xs[(HB) ^ 1][n][nq]  = pk4bf(v_lk(la));                        \
        *(int2*)&X2s[(HB) ^ 1][n][nq] = pk4bf(v_lk2(la));                       \
        __builtin_amdgcn_s_setprio(0);  /* leg1: yield to gate waves */         \
        bar_lgkm();       /* b2: x(T+1) visible (lgkm drain only) */            \
    } while (0)

        for (int t = 0; t < NS; t += 2) {
            LOSTEP(0, t);
            LOSTEP(1, t + 1);
        }
#undef LOSTEP

        // epilogue: y(NS-1) from X2s[0] (= lk2(x(NS)), written at T=NS-1,
        // visible via the loop's final bar_lgkm)
        if (lt < 2) {
            s16x8 p0 = *(const s16x8*)&X2s[0][n][quad * 8];
            s16x8 p1 = *(const s16x8*)&X2s[0][n][32 + quad * 8];
            f32x4 po = MFMA(wo0, p0, initO);
            po = MFMA(wo1, p1, po);
            *(f32x4*)(orow + (size_t)(NS - 1) * NF) = v_sigm_pre(po);
        }
    }
}

extern "C" void kernel_launch(void* const* d_in, const int* in_sizes, int n_in,
                              void* d_out, int out_size, void* d_ws, size_t ws_size,
                              hipStream_t stream) {
    const float* noise = (const float*)d_in[0];
    const float* Wihf  = (const float*)d_in[1];
    const float* Whhf  = (const float*)d_in[2];
    const float* bihf  = (const float*)d_in[3];
    const float* bhhf  = (const float*)d_in[4];
    const float* Wihb  = (const float*)d_in[5];
    const float* Whhb  = (const float*)d_in[6];
    const float* bihb  = (const float*)d_in[7];
    const float* bhhb  = (const float*)d_in[8];
    const float* Wlat  = (const float*)d_in[9];
    const float* blat  = (const float*)d_in[10];
    const float* Wout  = (const float*)d_in[11];
    const float* bout  = (const float*)d_in[12];

    grugan_kernel<<<dim3(NBATCH / MROW), dim3(768), 0, stream>>>(
        noise, Wihf, Whhf, bihf, bhhf, Wihb, Whhb, bihb, bhhb,
        Wlat, blat, Wout, bout, (float*)d_out);
}

// Round 9
// 1385.542 us; speedup vs baseline: 1.2540x; 1.0736x over previous
//
#include <hip/hip_runtime.h>
#include <hip/hip_bf16.h>

// GRU-GAN generator, MI355X. Round 18 — R17 base (best: 1380us) + R11's
// fragment-linear conflict-free LDS layout, isolated.
// Cross-round algebra: R16 showed lk_frag-in-outproj costs +229us; R11
// (+101us) bundled that same mistake WITH the fragment-linear layout ->
// layout alone ~= -130us, masked. The 1.78e7 bank-conflict cycles
// (~272 cy/CU/step) sit on the LDS-read critical path of both legs.
// Layout: per (buf[,dir]) tile, fragment f (k=32f..32f+31) stored
// [f][q][n][8] shorts -> wave b128 read addr = base + lane*16 (lane=n+16q):
// conflict-free by construction. int2 writes land 2-way (free).
// Everything else byte-identical to R17: 32 blocks x 768 threads,
//   waves 0-7 gates (leg1 prio1: x-read, 6 gi MFMA scale-folded, merged-rcp
//   elementwise + fma-denom, h write; leg2 prio0: 6 gh MFMA),
//   waves 8-11 latent (+out-proj on 8-9: trivial leg1 prio0, X2s read,
//   2 MFMA, pre-scaled sigm, un-drained store; leg2 prio1: h read both
//   dirs, 2+2 MFMA, lk/lk2, Xs+X2s writes).
// Numerics: identical values and op order as R17 -> absmax 0.00390625.

#define NBATCH 512
#define NH 64
#define NS 2048
#define NF 32
#define MROW 16

typedef short s16x8 __attribute__((ext_vector_type(8)));
typedef float f32x4 __attribute__((ext_vector_type(4)));

#define MFMA(a, b, c) __builtin_amdgcn_mfma_f32_16x16x32_bf16((a), (b), (c), 0, 0, 0)

#define NLOG2E  (-1.4426950408889634f)   // -log2(e)
#define N2LOG2E (-2.8853900817779268f)   // -2*log2(e)

__device__ __forceinline__ void bar_nodrain() {
    asm volatile("s_barrier" ::: "memory");
}

__device__ __forceinline__ void bar_lgkm() {
    asm volatile("s_waitcnt lgkmcnt(0)\n\ts_barrier" ::: "memory");
}

__device__ __forceinline__ short f2bf(float f) {
    return (short)((__float_as_uint(f) + 0x8000u) >> 16);
}

__device__ __forceinline__ f32x4 v_exp2(f32x4 a) {
    f32x4 r;
#pragma unroll
    for (int i = 0; i < 4; ++i) r[i] = __builtin_amdgcn_exp2f(a[i]);
    return r;
}

__device__ __forceinline__ f32x4 v_rcp(f32x4 a) {
    f32x4 r;
#pragma unroll
    for (int i = 0; i < 4; ++i) r[i] = __builtin_amdgcn_rcpf(a[i]);
    return r;
}

__device__ __forceinline__ f32x4 v_lk(f32x4 a) {
    f32x4 b = a * 0.01f;
    f32x4 r;
#pragma unroll
    for (int i = 0; i < 4; ++i) r[i] = fmaxf(a[i], b[i]);
    return r;
}

// lk(lk(x)) = max(x, 1e-4*x) in one stage
__device__ __forceinline__ f32x4 v_lk2(f32x4 a) {
    f32x4 b = a * 1e-4f;
    f32x4 r;
#pragma unroll
    for (int i = 0; i < 4; ++i) r[i] = fmaxf(a[i], b[i]);
    return r;
}

// sigmoid of pre-scaled input: a = -log2e * z  ->  1/(1+2^a)
__device__ __forceinline__ f32x4 v_sigm_pre(f32x4 a) {
    return v_rcp(v_exp2(a) + 1.0f);
}

__device__ __forceinline__ int2 pk4bf(f32x4 v) {
    union { __hip_bfloat162 b; int i; } lo, hi;
    float2 a; a.x = v[0]; a.y = v[1];
    float2 b; b.x = v[2]; b.y = v[3];
    lo.b = __float22bfloat162_rn(a);
    hi.b = __float22bfloat162_rn(b);
    int2 r; r.x = lo.i; r.y = hi.i;
    return r;
}

__device__ __forceinline__ s16x8 bfragW(const float* __restrict__ W, int ldk,
                                        int row, int kf, int quad, float scale) {
    const float* p = W + (size_t)row * ldk + kf * 32 + quad * 8;
    s16x8 r;
#pragma unroll
    for (int i = 0; i < 8; ++i) r[i] = f2bf(p[i] * scale);
    return r;
}

__device__ __forceinline__ f32x4 bias4s(const float* __restrict__ p, float scale) {
    const float4 v = *(const float4*)p;
    f32x4 r = {v.x * scale, v.y * scale, v.z * scale, v.w * scale};
    return r;
}

__global__ __launch_bounds__(768)
void grugan_kernel(const float* __restrict__ noise,
                   const float* __restrict__ Wihf, const float* __restrict__ Whhf,
                   const float* __restrict__ bihf, const float* __restrict__ bhhf,
                   const float* __restrict__ Wihb, const float* __restrict__ Whhb,
                   const float* __restrict__ bihb, const float* __restrict__ bhhb,
                   const float* __restrict__ Wlat, const float* __restrict__ blat,
                   const float* __restrict__ Wout, const float* __restrict__ bout,
                   float* __restrict__ out)
{
    // fragment-linear buffers: [hb][frag][q][n][8]; Hs adds [dir].
    __shared__ __align__(16) short Xs[2][2][4][16][8];
    __shared__ __align__(16) short X2s[2][2][4][16][8];
    __shared__ __align__(16) short Hs[2][2][2][4][16][8];

    const int tid  = threadIdx.x;
    const int wave = tid >> 6;
    const int lane = tid & 63;
    const int n    = lane & 15;   // batch row within tile
    const int quad = lane >> 4;
    const int row0 = blockIdx.x * MROW;

    // zero x(0) buffer (hb=0 half of Xs: 2*4*16*8 = 1024 shorts)
    for (int idx = tid; idx < 2 * 4 * 16 * 8; idx += 768)
        (&Xs[0][0][0][0][0])[idx] = 0;

    f32x4 hreg = {0.f, 0.f, 0.f, 0.f};
    const int gdir = wave >> 2;             // valid for waves 0-7
    const int gcb  = wave & 3;
    const int gjq  = gcb * 16 + quad * 4;
    // write-slot coords for the 4-col int2 at col0 = gcb*16 + quad*4:
    //   frag = c0>>5, q' = (c0&31)>>3, e = c0&7
    const int wfrag = gcb >> 1;
    const int wq    = ((gcb & 1) << 1) | (quad >> 1);
    const int we    = (quad & 1) << 2;
    if (wave < 8) {
        const float4 nz = *(const float4*)&noise[(size_t)(row0 + n) * NH + gjq];
        hreg[0] = nz.x; hreg[1] = nz.y; hreg[2] = nz.z; hreg[3] = nz.w;
        *(int2*)&Hs[0][gdir][wfrag][wq][n][we] = pk4bf(hreg);
    }
    __syncthreads();

    if (wave < 8) {
        // ======================= GATE WAVES =======================
        const int dir  = gdir;
        const int cb   = gcb;
        const int jrow = cb * 16 + n;
        const int jq   = gjq;
        const float* Wih = dir ? Wihb : Wihf;
        const float* Whh = dir ? Whhb : Whhf;
        const float* bih = dir ? bihb : bihf;
        const float* bhh = dir ? bhhb : bhhf;

        // r/z rows scaled by -log2e; n rows by -2log2e (scale folding)
        s16x8 wir0 = bfragW(Wih, NH,   0 + jrow, 0, quad, NLOG2E);
        s16x8 wir1 = bfragW(Wih, NH,   0 + jrow, 1, quad, NLOG2E);
        s16x8 wiz0 = bfragW(Wih, NH,  64 + jrow, 0, quad, NLOG2E);
        s16x8 wiz1 = bfragW(Wih, NH,  64 + jrow, 1, quad, NLOG2E);
        s16x8 win0 = bfragW(Wih, NH, 128 + jrow, 0, quad, N2LOG2E);
        s16x8 win1 = bfragW(Wih, NH, 128 + jrow, 1, quad, N2LOG2E);
        s16x8 whr0 = bfragW(Whh, NH,   0 + jrow, 0, quad, NLOG2E);
        s16x8 whr1 = bfragW(Whh, NH,   0 + jrow, 1, quad, NLOG2E);
        s16x8 whz0 = bfragW(Whh, NH,  64 + jrow, 0, quad, NLOG2E);
        s16x8 whz1 = bfragW(Whh, NH,  64 + jrow, 1, quad, NLOG2E);
        s16x8 whn0 = bfragW(Whh, NH, 128 + jrow, 0, quad, N2LOG2E);
        s16x8 whn1 = bfragW(Whh, NH, 128 + jrow, 1, quad, N2LOG2E);
        f32x4 initR, initZ;
        {
            f32x4 a = bias4s(&bih[jq], NLOG2E), b = bias4s(&bhh[jq], NLOG2E);
            initR = a + b;
            f32x4 c = bias4s(&bih[64 + jq], NLOG2E), d = bias4s(&bhh[64 + jq], NLOG2E);
            initZ = c + d;
        }
        const f32x4 initN1 = bias4s(&bih[128 + jq], N2LOG2E);
        const f32x4 initN2 = bias4s(&bhh[128 + jq], N2LOG2E);

        // prologue: gh accumulators for t=0 from h(0)
        f32x4 accR, accZ, accN2;
        {
            s16x8 ha0 = *(const s16x8*)&Hs[0][dir][0][quad][n][0];
            s16x8 ha1 = *(const s16x8*)&Hs[0][dir][1][quad][n][0];
            accR  = MFMA(whr0, ha0, initR);  accR  = MFMA(whr1, ha1, accR);
            accZ  = MFMA(whz0, ha0, initZ);  accZ  = MFMA(whz1, ha1, accZ);
            accN2 = MFMA(whn0, ha0, initN2); accN2 = MFMA(whn1, ha1, accN2);
        }

#define GSTEP(HB) do {                                                          \
        __builtin_amdgcn_s_setprio(1);  /* leg1: gates are the straggler */     \
        s16x8 xa0 = *(const s16x8*)&Xs[HB][0][quad][n][0];                      \
        s16x8 xa1 = *(const s16x8*)&Xs[HB][1][quad][n][0];                      \
        accR = MFMA(wir0, xa0, accR);   accR = MFMA(wir1, xa1, accR);           \
        accZ = MFMA(wiz0, xa0, accZ);   accZ = MFMA(wiz1, xa1, accZ);           \
        f32x4 accN1 = MFMA(win0, xa0, initN1);                                  \
        accN1 = MFMA(win1, xa1, accN1);                                         \
        /* scale-folded: accR/accZ = -log2e*(gi+gh), accN* = -2log2e*(...) */   \
        f32x4 eR = v_exp2(accR);                                                \
        f32x4 rr = v_rcp(eR + 1.0f);                                            \
        f32x4 eU = v_exp2(accN1 + rr * accN2);                                  \
        f32x4 eZ = v_exp2(accZ);                                                \
        f32x4 numer = (eZ + hreg) + eU * (hreg - eZ);                           \
        f32x4 tz    = eZ + 1.0f;                                                \
        f32x4 denom = eU * tz + tz;   /* fma((eU+1)(eZ+1)): -1 chain op */      \
        hreg = numer * v_rcp(denom);                                            \
        *(int2*)&Hs[(HB) ^ 1][dir][wfrag][wq][n][we] = pk4bf(hreg);             \
        __builtin_amdgcn_s_setprio(0);  /* leg2: yield to latent waves */       \
        __syncthreads();  /* b1: H(t+1) visible */                              \
        {                                                                       \
            s16x8 ha0 = *(const s16x8*)&Hs[(HB) ^ 1][dir][0][quad][n][0];       \
            s16x8 ha1 = *(const s16x8*)&Hs[(HB) ^ 1][dir][1][quad][n][0];       \
            accR  = MFMA(whr0, ha0, initR);  accR  = MFMA(whr1, ha1, accR);     \
            accZ  = MFMA(whz0, ha0, initZ);  accZ  = MFMA(whz1, ha1, accZ);     \
            accN2 = MFMA(whn0, ha0, initN2); accN2 = MFMA(whn1, ha1, accN2);    \
        }                                                                       \
        __syncthreads();  /* b2: x(t+1) visible */                              \
    } while (0)

        for (int t = 0; t < NS; t += 2) {
            GSTEP(0);
            GSTEP(1);
        }
#undef GSTEP
    } else {
        // =============== LATENT WAVES (+ fused OUT-PROJ on lt<2) ===============
        const int lt = wave & 3;
        s16x8 wl0 = bfragW(Wlat, 2 * NH, lt * 16 + n, 0, quad, 1.0f);
        s16x8 wl1 = bfragW(Wlat, 2 * NH, lt * 16 + n, 1, quad, 1.0f);
        s16x8 wl2 = bfragW(Wlat, 2 * NH, lt * 16 + n, 2, quad, 1.0f);
        s16x8 wl3 = bfragW(Wlat, 2 * NH, lt * 16 + n, 3, quad, 1.0f);
        const f32x4 initL = bias4s(&blat[lt * 16 + quad * 4], 1.0f);
        // Xs/X2s write-slot coords for this wave's 4 latent cols
        const int lfrag = lt >> 1;
        const int lq    = ((lt & 1) << 1) | (quad >> 1);
        const int le    = (quad & 1) << 2;

        // out-proj state (waves 8-9 only: f-tile f0 = lt*16), pre-scaled -log2e
        s16x8 wo0 = {}, wo1 = {};
        f32x4 initO = {0.f, 0.f, 0.f, 0.f};
        float* orow = nullptr;
        if (lt < 2) {
            const int f0 = lt * 16;
            wo0   = bfragW(Wout, NH, f0 + n, 0, quad, NLOG2E);
            wo1   = bfragW(Wout, NH, f0 + n, 1, quad, NLOG2E);
            initO = bias4s(&bout[f0 + quad * 4], NLOG2E);
            orow  = out + (size_t)(row0 + n) * (NS * NF) + f0 + quad * 4;
        }
        const f32x4 zero4 = {0.f, 0.f, 0.f, 0.f};

#define LOSTEP(HB, T) do {                                                      \
        if (lt < 2 && (T) > 0) {                                                \
            /* leg1 (prio 0 — slack, must stay SHORT): out-proj of y(T-1) */    \
            /* from X2s[HB]; store never drained (raw barriers).          */    \
            s16x8 p0 = *(const s16x8*)&X2s[HB][0][quad][n][0];                  \
            s16x8 p1 = *(const s16x8*)&X2s[HB][1][quad][n][0];                  \
            f32x4 po = MFMA(wo0, p0, initO);                                    \
            po = MFMA(wo1, p1, po);                                             \
            *(f32x4*)(orow + (size_t)((T) - 1) * NF) = v_sigm_pre(po);          \
        }                                                                       \
        bar_nodrain();    /* b1: H(T+1) visible (we have nothing pending) */    \
        __builtin_amdgcn_s_setprio(1);  /* leg2: latent is the straggler */     \
        s16x8 fa0 = *(const s16x8*)&Hs[(HB) ^ 1][0][0][quad][n][0];             \
        s16x8 fa1 = *(const s16x8*)&Hs[(HB) ^ 1][0][1][quad][n][0];             \
        s16x8 ba0 = *(const s16x8*)&Hs[(HB) ^ 1][1][0][quad][n][0];             \
        s16x8 ba1 = *(const s16x8*)&Hs[(HB) ^ 1][1][1][quad][n][0];             \
        f32x4 lac1 = MFMA(wl0, fa0, initL);                                     \
        lac1 = MFMA(wl1, fa1, lac1);                                            \
        f32x4 lac2 = MFMA(wl2, ba0, zero4);                                     \
        lac2 = MFMA(wl3, ba1, lac2);                                            \
        f32x4 la = lac1 + lac2;                                                 \
        *(int2*)&Xs[(HB) ^ 1][lfrag][lq][n][le]  = pk4bf(v_lk(la));             \
        *(int2*)&X2s[(HB) ^ 1][lfrag][lq][n][le] = pk4bf(v_lk2(la));            \
        __builtin_amdgcn_s_setprio(0);  /* leg1: yield to gate waves */         \
        bar_lgkm();       /* b2: x(T+1) visible (lgkm drain only) */            \
    } while (0)

        for (int t = 0; t < NS; t += 2) {
            LOSTEP(0, t);
            LOSTEP(1, t + 1);
        }
#undef LOSTEP

        // epilogue: y(NS-1) from X2s[0] (= lk2(x(NS)), written at T=NS-1,
        // visible via the loop's final bar_lgkm)
        if (lt < 2) {
            s16x8 p0 = *(const s16x8*)&X2s[0][0][quad][n][0];
            s16x8 p1 = *(const s16x8*)&X2s[0][1][quad][n][0];
            f32x4 po = MFMA(wo0, p0, initO);
            po = MFMA(wo1, p1, po);
            *(f32x4*)(orow + (size_t)(NS - 1) * NF) = v_sigm_pre(po);
        }
    }
}

extern "C" void kernel_launch(void* const* d_in, const int* in_sizes, int n_in,
                              void* d_out, int out_size, void* d_ws, size_t ws_size,
                              hipStream_t stream) {
    const float* noise = (const float*)d_in[0];
    const float* Wihf  = (const float*)d_in[1];
    const float* Whhf  = (const float*)d_in[2];
    const float* bihf  = (const float*)d_in[3];
    const float* bhhf  = (const float*)d_in[4];
    const float* Wihb  = (const float*)d_in[5];
    const float* Whhb  = (const float*)d_in[6];
    const float* bihb  = (const float*)d_in[7];
    const float* bhhb  = (const float*)d_in[8];
    const float* Wlat  = (const float*)d_in[9];
    const float* blat  = (const float*)d_in[10];
    const float* Wout  = (const float*)d_in[11];
    const float* bout  = (const float*)d_in[12];

    grugan_kernel<<<dim3(NBATCH / MROW), dim3(768), 0, stream>>>(
        noise, Wihf, Whhf, bihf, bhhf, Wihb, Whhb, bihb, bhhb,
        Wlat, blat, Wout, bout, (float*)d_out);
}

// Round 13
// 1380.017 us; speedup vs baseline: 1.2591x; 1.0040x over previous
//
#include <hip/hip_runtime.h>
#include <hip/hip_bf16.h>

// GRU-GAN generator, MI355X. Round 22 — resubmit of R21 (infra failure, the
// kernel never ran). Packed-FP32 via C vector ops (safe).
// R19: v_pk_max_f32 doesn't exist on gfx950 (compile-verified).
// R20: raw-mnemonic v_pk_* inline asm MISCOMPUTES (absmax 0.415) — likely
//      op_sel_hi defaulting wrong or unaligned VGPR pair; raw VOP3P asm
//      abandoned.
// R21/R22: same structure, but pk2_* are plain C v2f32 ops (a+b, a*b,
//      __builtin_elementwise_fma) — LLVM gfx90a+ has ISel patterns
//      (HasPackedFP32Ops) mapping v2f32 fadd/fmul/fma -> V_PK_*_F32.
//      Correctness is compiler-guaranteed (rounding-identical to R18);
//      the bench tells us whether packing happened (dur ~1220) or not
//      (dur ~= R18's 1266, lever dead).
// Base R18 (best: 1266us): fragment-linear LDS, 12 waves, setprio roles,
// scale folding, un-drained y-stores, fma-folded denom.

#define NBATCH 512
#define NH 64
#define NS 2048
#define NF 32
#define MROW 16

typedef short s16x8 __attribute__((ext_vector_type(8)));
typedef float f32x4 __attribute__((ext_vector_type(4)));
typedef float f32x2 __attribute__((ext_vector_type(2)));

#define MFMA(a, b, c) __builtin_amdgcn_mfma_f32_16x16x32_bf16((a), (b), (c), 0, 0, 0)

#define NLOG2E  (-1.4426950408889634f)   // -log2(e)
#define N2LOG2E (-2.8853900817779268f)   // -2*log2(e)

__device__ __forceinline__ void bar_nodrain() {
    asm volatile("s_barrier" ::: "memory");
}

__device__ __forceinline__ void bar_lgkm() {
    asm volatile("s_waitcnt lgkmcnt(0)\n\ts_barrier" ::: "memory");
}

__device__ __forceinline__ short f2bf(float f) {
    return (short)((__float_as_uint(f) + 0x8000u) >> 16);
}

__device__ __forceinline__ f32x4 v_exp2(f32x4 a) {
    f32x4 r;
#pragma unroll
    for (int i = 0; i < 4; ++i) r[i] = __builtin_amdgcn_exp2f(a[i]);
    return r;
}

__device__ __forceinline__ f32x4 v_rcp(f32x4 a) {
    f32x4 r;
#pragma unroll
    for (int i = 0; i < 4; ++i) r[i] = __builtin_amdgcn_rcpf(a[i]);
    return r;
}

// ---------------- packed-FP32 staging: C v2f32 ops (ISel may select
// V_PK_ADD/MUL/FMA_F32 on gfx90a+; semantics compiler-guaranteed) ---------
__device__ __forceinline__ f32x2 lo2(f32x4 v) { f32x2 r; r[0] = v[0]; r[1] = v[1]; return r; }
__device__ __forceinline__ f32x2 hi2(f32x4 v) { f32x2 r; r[0] = v[2]; r[1] = v[3]; return r; }
__device__ __forceinline__ f32x4 mk4(f32x2 a, f32x2 b) {
    f32x4 r; r[0] = a[0]; r[1] = a[1]; r[2] = b[0]; r[3] = b[1]; return r;
}

__device__ __forceinline__ f32x2 pk2_add(f32x2 a, f32x2 b) { return a + b; }
__device__ __forceinline__ f32x2 pk2_mul(f32x2 a, f32x2 b) { return a * b; }
__device__ __forceinline__ f32x2 pk2_fma(f32x2 a, f32x2 b, f32x2 c) {
    return __builtin_elementwise_fma(a, b, c);
}

__device__ __forceinline__ f32x4 pk_add(f32x4 a, f32x4 b) {
    return mk4(pk2_add(lo2(a), lo2(b)), pk2_add(hi2(a), hi2(b)));
}
__device__ __forceinline__ f32x4 pk_addc(f32x4 a, f32x2 c) {
    return mk4(pk2_add(lo2(a), c), pk2_add(hi2(a), c));
}
__device__ __forceinline__ f32x4 pk_mul(f32x4 a, f32x4 b) {
    return mk4(pk2_mul(lo2(a), lo2(b)), pk2_mul(hi2(a), hi2(b)));
}
__device__ __forceinline__ f32x4 pk_fma(f32x4 a, f32x4 b, f32x4 c) {
    return mk4(pk2_fma(lo2(a), lo2(b), lo2(c)), pk2_fma(hi2(a), hi2(b), hi2(c)));
}
// a*c + b  (c = 2-wide splat constant)
__device__ __forceinline__ f32x4 pk_fmac(f32x4 a, f32x2 c, f32x4 b) {
    return mk4(pk2_fma(lo2(a), c, lo2(b)), pk2_fma(hi2(a), c, hi2(b)));
}
// leaky: max(a, slope*a) — packed mul, scalar max (no v_pk_max_f32 on gfx950)
__device__ __forceinline__ f32x4 pk_lk(f32x4 a, f32x2 slope) {
    f32x4 s = mk4(pk2_mul(lo2(a), slope), pk2_mul(hi2(a), slope));
    f32x4 r;
#pragma unroll
    for (int i = 0; i < 4; ++i) r[i] = fmaxf(a[i], s[i]);
    return r;
}

// sigmoid of pre-scaled input: a = -log2e * z  ->  1/(1+2^a)  (slack leg)
__device__ __forceinline__ f32x4 v_sigm_pre(f32x4 a) {
    f32x4 e = v_exp2(a);
    f32x4 r;
#pragma unroll
    for (int i = 0; i < 4; ++i) r[i] = __builtin_amdgcn_rcpf(e[i] + 1.0f);
    return r;
}

__device__ __forceinline__ int2 pk4bf(f32x4 v) {
    union { __hip_bfloat162 b; int i; } lo, hi;
    float2 a; a.x = v[0]; a.y = v[1];
    float2 b; b.x = v[2]; b.y = v[3];
    lo.b = __float22bfloat162_rn(a);
    hi.b = __float22bfloat162_rn(b);
    int2 r; r.x = lo.i; r.y = hi.i;
    return r;
}

__device__ __forceinline__ s16x8 bfragW(const float* __restrict__ W, int ldk,
                                        int row, int kf, int quad, float scale) {
    const float* p = W + (size_t)row * ldk + kf * 32 + quad * 8;
    s16x8 r;
#pragma unroll
    for (int i = 0; i < 8; ++i) r[i] = f2bf(p[i] * scale);
    return r;
}

__device__ __forceinline__ f32x4 bias4s(const float* __restrict__ p, float scale) {
    const float4 v = *(const float4*)p;
    f32x4 r = {v.x * scale, v.y * scale, v.z * scale, v.w * scale};
    return r;
}

__global__ __launch_bounds__(768)
void grugan_kernel(const float* __restrict__ noise,
                   const float* __restrict__ Wihf, const float* __restrict__ Whhf,
                   const float* __restrict__ bihf, const float* __restrict__ bhhf,
                   const float* __restrict__ Wihb, const float* __restrict__ Whhb,
                   const float* __restrict__ bihb, const float* __restrict__ bhhb,
                   const float* __restrict__ Wlat, const float* __restrict__ blat,
                   const float* __restrict__ Wout, const float* __restrict__ bout,
                   float* __restrict__ out)
{
    // fragment-linear buffers: [hb][frag][q][n][8]; Hs adds [dir].
    __shared__ __align__(16) short Xs[2][2][4][16][8];
    __shared__ __align__(16) short X2s[2][2][4][16][8];
    __shared__ __align__(16) short Hs[2][2][2][4][16][8];

    const int tid  = threadIdx.x;
    const int wave = tid >> 6;
    const int lane = tid & 63;
    const int n    = lane & 15;   // batch row within tile
    const int quad = lane >> 4;
    const int row0 = blockIdx.x * MROW;

    // zero x(0) buffer (hb=0 half of Xs: 2*4*16*8 = 1024 shorts)
    for (int idx = tid; idx < 2 * 4 * 16 * 8; idx += 768)
        (&Xs[0][0][0][0][0])[idx] = 0;

    f32x4 hreg = {0.f, 0.f, 0.f, 0.f};
    const int gdir = wave >> 2;             // valid for waves 0-7
    const int gcb  = wave & 3;
    const int gjq  = gcb * 16 + quad * 4;
    // write-slot coords for the 4-col int2 at col0 = gcb*16 + quad*4:
    //   frag = c0>>5, q' = (c0&31)>>3, e = c0&7
    const int wfrag = gcb >> 1;
    const int wq    = ((gcb & 1) << 1) | (quad >> 1);
    const int we    = (quad & 1) << 2;
    if (wave < 8) {
        const float4 nz = *(const float4*)&noise[(size_t)(row0 + n) * NH + gjq];
        hreg[0] = nz.x; hreg[1] = nz.y; hreg[2] = nz.z; hreg[3] = nz.w;
        *(int2*)&Hs[0][gdir][wfrag][wq][n][we] = pk4bf(hreg);
    }
    __syncthreads();

    if (wave < 8) {
        // ======================= GATE WAVES =======================
        const int dir  = gdir;
        const int cb   = gcb;
        const int jrow = cb * 16 + n;
        const int jq   = gjq;
        const float* Wih = dir ? Wihb : Wihf;
        const float* Whh = dir ? Whhb : Whhf;
        const float* bih = dir ? bihb : bihf;
        const float* bhh = dir ? bhhb : bhhf;

        // r/z rows scaled by -log2e; n rows by -2log2e (scale folding)
        s16x8 wir0 = bfragW(Wih, NH,   0 + jrow, 0, quad, NLOG2E);
        s16x8 wir1 = bfragW(Wih, NH,   0 + jrow, 1, quad, NLOG2E);
        s16x8 wiz0 = bfragW(Wih, NH,  64 + jrow, 0, quad, NLOG2E);
        s16x8 wiz1 = bfragW(Wih, NH,  64 + jrow, 1, quad, NLOG2E);
        s16x8 win0 = bfragW(Wih, NH, 128 + jrow, 0, quad, N2LOG2E);
        s16x8 win1 = bfragW(Wih, NH, 128 + jrow, 1, quad, N2LOG2E);
        s16x8 whr0 = bfragW(Whh, NH,   0 + jrow, 0, quad, NLOG2E);
        s16x8 whr1 = bfragW(Whh, NH,   0 + jrow, 1, quad, NLOG2E);
        s16x8 whz0 = bfragW(Whh, NH,  64 + jrow, 0, quad, NLOG2E);
        s16x8 whz1 = bfragW(Whh, NH,  64 + jrow, 1, quad, NLOG2E);
        s16x8 whn0 = bfragW(Whh, NH, 128 + jrow, 0, quad, N2LOG2E);
        s16x8 whn1 = bfragW(Whh, NH, 128 + jrow, 1, quad, N2LOG2E);
        f32x4 initR, initZ;
        {
            f32x4 a = bias4s(&bih[jq], NLOG2E), b = bias4s(&bhh[jq], NLOG2E);
            initR = a + b;
            f32x4 c = bias4s(&bih[64 + jq], NLOG2E), d = bias4s(&bhh[64 + jq], NLOG2E);
            initZ = c + d;
        }
        const f32x4 initN1 = bias4s(&bih[128 + jq], N2LOG2E);
        const f32x4 initN2 = bias4s(&bhh[128 + jq], N2LOG2E);

        const f32x2 c_one  = { 1.0f,  1.0f};
        const f32x2 c_neg1 = {-1.0f, -1.0f};

        // prologue: gh accumulators for t=0 from h(0)
        f32x4 accR, accZ, accN2;
        {
            s16x8 ha0 = *(const s16x8*)&Hs[0][dir][0][quad][n][0];
            s16x8 ha1 = *(const s16x8*)&Hs[0][dir][1][quad][n][0];
            accR  = MFMA(whr0, ha0, initR);  accR  = MFMA(whr1, ha1, accR);
            accZ  = MFMA(whz0, ha0, initZ);  accZ  = MFMA(whz1, ha1, accZ);
            accN2 = MFMA(whn0, ha0, initN2); accN2 = MFMA(whn1, ha1, accN2);
        }

#define GSTEP(HB) do {                                                          \
        __builtin_amdgcn_s_setprio(1);  /* leg1: gates are the straggler */     \
        s16x8 xa0 = *(const s16x8*)&Xs[HB][0][quad][n][0];                      \
        s16x8 xa1 = *(const s16x8*)&Xs[HB][1][quad][n][0];                      \
        accR = MFMA(wir0, xa0, accR);   accR = MFMA(wir1, xa1, accR);           \
        accZ = MFMA(wiz0, xa0, accZ);   accZ = MFMA(wiz1, xa1, accZ);           \
        f32x4 accN1 = MFMA(win0, xa0, initN1);                                  \
        accN1 = MFMA(win1, xa1, accN1);                                         \
        /* scale-folded merged-rcp GRU update, v2f32-staged (rounding-     */   \
        /* identical to the scalar fma/add/mul sequence):                  */   \
        f32x4 eR = v_exp2(accR);                                                \
        f32x4 rr = v_rcp(pk_addc(eR, c_one));                                   \
        f32x4 u  = pk_fma(rr, accN2, accN1);                                    \
        f32x4 eU = v_exp2(u);                                                   \
        f32x4 eZ = v_exp2(accZ);                                                \
        f32x4 t1 = pk_add(eZ, hreg);                                            \
        f32x4 t2 = pk_fmac(eZ, c_neg1, hreg);   /* hreg - eZ */                 \
        f32x4 numer = pk_fma(eU, t2, t1);                                       \
        f32x4 tz    = pk_addc(eZ, c_one);                                       \
        f32x4 denom = pk_fma(eU, tz, tz);       /* (eU+1)(eZ+1) via fma */      \
        hreg = pk_mul(numer, v_rcp(denom));                                     \
        *(int2*)&Hs[(HB) ^ 1][dir][wfrag][wq][n][we] = pk4bf(hreg);             \
        __builtin_amdgcn_s_setprio(0);  /* leg2: yield to latent waves */       \
        __syncthreads();  /* b1: H(t+1) visible */                              \
        {                                                                       \
            s16x8 ha0 = *(const s16x8*)&Hs[(HB) ^ 1][dir][0][quad][n][0];       \
            s16x8 ha1 = *(const s16x8*)&Hs[(HB) ^ 1][dir][1][quad][n][0];       \
            accR  = MFMA(whr0, ha0, initR);  accR  = MFMA(whr1, ha1, accR);     \
            accZ  = MFMA(whz0, ha0, initZ);  accZ  = MFMA(whz1, ha1, accZ);     \
            accN2 = MFMA(whn0, ha0, initN2); accN2 = MFMA(whn1, ha1, accN2);    \
        }                                                                       \
        __syncthreads();  /* b2: x(t+1) visible */                              \
    } while (0)

        for (int t = 0; t < NS; t += 2) {
            GSTEP(0);
            GSTEP(1);
        }
#undef GSTEP
    } else {
        // =============== LATENT WAVES (+ fused OUT-PROJ on lt<2) ===============
        const int lt = wave & 3;
        s16x8 wl0 = bfragW(Wlat, 2 * NH, lt * 16 + n, 0, quad, 1.0f);
        s16x8 wl1 = bfragW(Wlat, 2 * NH, lt * 16 + n, 1, quad, 1.0f);
        s16x8 wl2 = bfragW(Wlat, 2 * NH, lt * 16 + n, 2, quad, 1.0f);
        s16x8 wl3 = bfragW(Wlat, 2 * NH, lt * 16 + n, 3, quad, 1.0f);
        const f32x4 initL = bias4s(&blat[lt * 16 + quad * 4], 1.0f);
        // Xs/X2s write-slot coords for this wave's 4 latent cols
        const int lfrag = lt >> 1;
        const int lq    = ((lt & 1) << 1) | (quad >> 1);
        const int le    = (quad & 1) << 2;

        const f32x2 c_lk  = {1e-2f, 1e-2f};
        const f32x2 c_lk2 = {1e-4f, 1e-4f};

        // out-proj state (waves 8-9 only: f-tile f0 = lt*16), pre-scaled -log2e
        s16x8 wo0 = {}, wo1 = {};
        f32x4 initO = {0.f, 0.f, 0.f, 0.f};
        float* orow = nullptr;
        if (lt < 2) {
            const int f0 = lt * 16;
            wo0   = bfragW(Wout, NH, f0 + n, 0, quad, NLOG2E);
            wo1   = bfragW(Wout, NH, f0 + n, 1, quad, NLOG2E);
            initO = bias4s(&bout[f0 + quad * 4], NLOG2E);
            orow  = out + (size_t)(row0 + n) * (NS * NF) + f0 + quad * 4;
        }
        const f32x4 zero4 = {0.f, 0.f, 0.f, 0.f};

#define LOSTEP(HB, T) do {                                                      \
        if (lt < 2 && (T) > 0) {                                                \
            /* leg1 (prio 0 — slack, must stay SHORT): out-proj of y(T-1) */    \
            /* from X2s[HB]; store never drained (raw barriers).          */    \
            s16x8 p0 = *(const s16x8*)&X2s[HB][0][quad][n][0];                  \
            s16x8 p1 = *(const s16x8*)&X2s[HB][1][quad][n][0];                  \
            f32x4 po = MFMA(wo0, p0, initO);                                    \
            po = MFMA(wo1, p1, po);                                             \
            *(f32x4*)(orow + (size_t)((T) - 1) * NF) = v_sigm_pre(po);          \
        }                                                                       \
        bar_nodrain();    /* b1: H(T+1) visible (we have nothing pending) */    \
        __builtin_amdgcn_s_setprio(1);  /* leg2: latent is the straggler */     \
        s16x8 fa0 = *(const s16x8*)&Hs[(HB) ^ 1][0][0][quad][n][0];             \
        s16x8 fa1 = *(const s16x8*)&Hs[(HB) ^ 1][0][1][quad][n][0];             \
        s16x8 ba0 = *(const s16x8*)&Hs[(HB) ^ 1][1][0][quad][n][0];             \
        s16x8 ba1 = *(const s16x8*)&Hs[(HB) ^ 1][1][1][quad][n][0];             \
        f32x4 lac1 = MFMA(wl0, fa0, initL);                                     \
        lac1 = MFMA(wl1, fa1, lac1);                                            \
        f32x4 lac2 = MFMA(wl2, ba0, zero4);                                     \
        lac2 = MFMA(wl3, ba1, lac2);                                            \
        f32x4 la = pk_add(lac1, lac2);                                          \
        *(int2*)&Xs[(HB) ^ 1][lfrag][lq][n][le]  = pk4bf(pk_lk(la, c_lk));      \
        *(int2*)&X2s[(HB) ^ 1][lfrag][lq][n][le] = pk4bf(pk_lk(la, c_lk2));     \
        __builtin_amdgcn_s_setprio(0);  /* leg1: yield to gate waves */         \
        bar_lgkm();       /* b2: x(T+1) visible (lgkm drain only) */            \
    } while (0)

        for (int t = 0; t < NS; t += 2) {
            LOSTEP(0, t);
            LOSTEP(1, t + 1);
        }
#undef LOSTEP

        // epilogue: y(NS-1) from X2s[0] (= lk2(x(NS)), written at T=NS-1,
        // visible via the loop's final bar_lgkm)
        if (lt < 2) {
            s16x8 p0 = *(const s16x8*)&X2s[0][0][quad][n][0];
            s16x8 p1 = *(const s16x8*)&X2s[0][1][quad][n][0];
            f32x4 po = MFMA(wo0, p0, initO);
            po = MFMA(wo1, p1, po);
            *(f32x4*)(orow + (size_t)(NS - 1) * NF) = v_sigm_pre(po);
        }
    }
}

extern "C" void kernel_launch(void* const* d_in, const int* in_sizes, int n_in,
                              void* d_out, int out_size, void* d_ws, size_t ws_size,
                              hipStream_t stream) {
    const float* noise = (const float*)d_in[0];
    const float* Wihf  = (const float*)d_in[1];
    const float* Whhf  = (const float*)d_in[2];
    const float* bihf  = (const float*)d_in[3];
    const float* bhhf  = (const float*)d_in[4];
    const float* Wihb  = (const float*)d_in[5];
    const float* Whhb  = (const float*)d_in[6];
    const float* bihb  = (const float*)d_in[7];
    const float* bhhb  = (const float*)d_in[8];
    const float* Wlat  = (const float*)d_in[9];
    const float* blat  = (const float*)d_in[10];
    const float* Wout  = (const float*)d_in[11];
    const float* bout  = (const float*)d_in[12];

    grugan_kernel<<<dim3(NBATCH / MROW), dim3(768), 0, stream>>>(
        noise, Wihf, Whhf, bihf, bhhf, Wihb, Whhb, bihb, bhhb,
        Wlat, blat, Wout, bout, (float*)d_out);
}

// Round 14
// 1378.751 us; speedup vs baseline: 1.2602x; 1.0009x over previous
//
#include <hip/hip_runtime.h>
#include <hip/hip_bf16.h>

// GRU-GAN generator, MI355X. Round 23 — R22 base (best: 1265us) + gate leg1
// MFMA issue order accR -> accN1 -> accZ, ISOLATED (was bundled into R16's
// lk_frag regression, never measured alone).
// Mechanism: elementwise critical chain is accR->eR->rr->u(accN1)->eU;
// issuing accN1's MFMAs right after accR's starts u ~2 issue-slots earlier;
// eZ (tail-only) overlaps. Per-accumulator association order unchanged ->
// bit-identical numerics (absmax must stay 0.00390625).
// R22 settled: v2f32 staging == R18 codegen (packing lever dead).
// If this round is neutral, the structure is at its latency floor:
// 1483 cy/step measured vs ~750-910 cy serial chain x 1.6-2x contention
// dilation (VALU ~54%, MFMA ~31% on the 32 active CUs); parallelism capped
// at 32 blocks by the batch-tile recurrence. All other levers tested.
// Base: fragment-linear LDS, 12 waves, setprio roles, scale folding,
// un-drained y-stores, fma-folded denom.

#define NBATCH 512
#define NH 64
#define NS 2048
#define NF 32
#define MROW 16

typedef short s16x8 __attribute__((ext_vector_type(8)));
typedef float f32x4 __attribute__((ext_vector_type(4)));
typedef float f32x2 __attribute__((ext_vector_type(2)));

#define MFMA(a, b, c) __builtin_amdgcn_mfma_f32_16x16x32_bf16((a), (b), (c), 0, 0, 0)

#define NLOG2E  (-1.4426950408889634f)   // -log2(e)
#define N2LOG2E (-2.8853900817779268f)   // -2*log2(e)

__device__ __forceinline__ void bar_nodrain() {
    asm volatile("s_barrier" ::: "memory");
}

__device__ __forceinline__ void bar_lgkm() {
    asm volatile("s_waitcnt lgkmcnt(0)\n\ts_barrier" ::: "memory");
}

__device__ __forceinline__ short f2bf(float f) {
    return (short)((__float_as_uint(f) + 0x8000u) >> 16);
}

__device__ __forceinline__ f32x4 v_exp2(f32x4 a) {
    f32x4 r;
#pragma unroll
    for (int i = 0; i < 4; ++i) r[i] = __builtin_amdgcn_exp2f(a[i]);
    return r;
}

__device__ __forceinline__ f32x4 v_rcp(f32x4 a) {
    f32x4 r;
#pragma unroll
    for (int i = 0; i < 4; ++i) r[i] = __builtin_amdgcn_rcpf(a[i]);
    return r;
}

// ---------------- v2f32 staging (R22; codegen == scalar, kept for form) ----
__device__ __forceinline__ f32x2 lo2(f32x4 v) { f32x2 r; r[0] = v[0]; r[1] = v[1]; return r; }
__device__ __forceinline__ f32x2 hi2(f32x4 v) { f32x2 r; r[0] = v[2]; r[1] = v[3]; return r; }
__device__ __forceinline__ f32x4 mk4(f32x2 a, f32x2 b) {
    f32x4 r; r[0] = a[0]; r[1] = a[1]; r[2] = b[0]; r[3] = b[1]; return r;
}

__device__ __forceinline__ f32x2 pk2_add(f32x2 a, f32x2 b) { return a + b; }
__device__ __forceinline__ f32x2 pk2_mul(f32x2 a, f32x2 b) { return a * b; }
__device__ __forceinline__ f32x2 pk2_fma(f32x2 a, f32x2 b, f32x2 c) {
    return __builtin_elementwise_fma(a, b, c);
}

__device__ __forceinline__ f32x4 pk_add(f32x4 a, f32x4 b) {
    return mk4(pk2_add(lo2(a), lo2(b)), pk2_add(hi2(a), hi2(b)));
}
__device__ __forceinline__ f32x4 pk_addc(f32x4 a, f32x2 c) {
    return mk4(pk2_add(lo2(a), c), pk2_add(hi2(a), c));
}
__device__ __forceinline__ f32x4 pk_mul(f32x4 a, f32x4 b) {
    return mk4(pk2_mul(lo2(a), lo2(b)), pk2_mul(hi2(a), hi2(b)));
}
__device__ __forceinline__ f32x4 pk_fma(f32x4 a, f32x4 b, f32x4 c) {
    return mk4(pk2_fma(lo2(a), lo2(b), lo2(c)), pk2_fma(hi2(a), hi2(b), hi2(c)));
}
// a*c + b  (c = 2-wide splat constant)
__device__ __forceinline__ f32x4 pk_fmac(f32x4 a, f32x2 c, f32x4 b) {
    return mk4(pk2_fma(lo2(a), c, lo2(b)), pk2_fma(hi2(a), c, hi2(b)));
}
// leaky: max(a, slope*a) — mul + scalar max (no v_pk_max_f32 on gfx950)
__device__ __forceinline__ f32x4 pk_lk(f32x4 a, f32x2 slope) {
    f32x4 s = mk4(pk2_mul(lo2(a), slope), pk2_mul(hi2(a), slope));
    f32x4 r;
#pragma unroll
    for (int i = 0; i < 4; ++i) r[i] = fmaxf(a[i], s[i]);
    return r;
}

// sigmoid of pre-scaled input: a = -log2e * z  ->  1/(1+2^a)  (slack leg)
__device__ __forceinline__ f32x4 v_sigm_pre(f32x4 a) {
    f32x4 e = v_exp2(a);
    f32x4 r;
#pragma unroll
    for (int i = 0; i < 4; ++i) r[i] = __builtin_amdgcn_rcpf(e[i] + 1.0f);
    return r;
}

__device__ __forceinline__ int2 pk4bf(f32x4 v) {
    union { __hip_bfloat162 b; int i; } lo, hi;
    float2 a; a.x = v[0]; a.y = v[1];
    float2 b; b.x = v[2]; b.y = v[3];
    lo.b = __float22bfloat162_rn(a);
    hi.b = __float22bfloat162_rn(b);
    int2 r; r.x = lo.i; r.y = hi.i;
    return r;
}

__device__ __forceinline__ s16x8 bfragW(const float* __restrict__ W, int ldk,
                                        int row, int kf, int quad, float scale) {
    const float* p = W + (size_t)row * ldk + kf * 32 + quad * 8;
    s16x8 r;
#pragma unroll
    for (int i = 0; i < 8; ++i) r[i] = f2bf(p[i] * scale);
    return r;
}

__device__ __forceinline__ f32x4 bias4s(const float* __restrict__ p, float scale) {
    const float4 v = *(const float4*)p;
    f32x4 r = {v.x * scale, v.y * scale, v.z * scale, v.w * scale};
    return r;
}

__global__ __launch_bounds__(768)
void grugan_kernel(const float* __restrict__ noise,
                   const float* __restrict__ Wihf, const float* __restrict__ Whhf,
                   const float* __restrict__ bihf, const float* __restrict__ bhhf,
                   const float* __restrict__ Wihb, const float* __restrict__ Whhb,
                   const float* __restrict__ bihb, const float* __restrict__ bhhb,
                   const float* __restrict__ Wlat, const float* __restrict__ blat,
                   const float* __restrict__ Wout, const float* __restrict__ bout,
                   float* __restrict__ out)
{
    // fragment-linear buffers: [hb][frag][q][n][8]; Hs adds [dir].
    __shared__ __align__(16) short Xs[2][2][4][16][8];
    __shared__ __align__(16) short X2s[2][2][4][16][8];
    __shared__ __align__(16) short Hs[2][2][2][4][16][8];

    const int tid  = threadIdx.x;
    const int wave = tid >> 6;
    const int lane = tid & 63;
    const int n    = lane & 15;   // batch row within tile
    const int quad = lane >> 4;
    const int row0 = blockIdx.x * MROW;

    // zero x(0) buffer (hb=0 half of Xs: 2*4*16*8 = 1024 shorts)
    for (int idx = tid; idx < 2 * 4 * 16 * 8; idx += 768)
        (&Xs[0][0][0][0][0])[idx] = 0;

    f32x4 hreg = {0.f, 0.f, 0.f, 0.f};
    const int gdir = wave >> 2;             // valid for waves 0-7
    const int gcb  = wave & 3;
    const int gjq  = gcb * 16 + quad * 4;
    // write-slot coords for the 4-col int2 at col0 = gcb*16 + quad*4:
    //   frag = c0>>5, q' = (c0&31)>>3, e = c0&7
    const int wfrag = gcb >> 1;
    const int wq    = ((gcb & 1) << 1) | (quad >> 1);
    const int we    = (quad & 1) << 2;
    if (wave < 8) {
        const float4 nz = *(const float4*)&noise[(size_t)(row0 + n) * NH + gjq];
        hreg[0] = nz.x; hreg[1] = nz.y; hreg[2] = nz.z; hreg[3] = nz.w;
        *(int2*)&Hs[0][gdir][wfrag][wq][n][we] = pk4bf(hreg);
    }
    __syncthreads();

    if (wave < 8) {
        // ======================= GATE WAVES =======================
        const int dir  = gdir;
        const int cb   = gcb;
        const int jrow = cb * 16 + n;
        const int jq   = gjq;
        const float* Wih = dir ? Wihb : Wihf;
        const float* Whh = dir ? Whhb : Whhf;
        const float* bih = dir ? bihb : bihf;
        const float* bhh = dir ? bhhb : bhhf;

        // r/z rows scaled by -log2e; n rows by -2log2e (scale folding)
        s16x8 wir0 = bfragW(Wih, NH,   0 + jrow, 0, quad, NLOG2E);
        s16x8 wir1 = bfragW(Wih, NH,   0 + jrow, 1, quad, NLOG2E);
        s16x8 wiz0 = bfragW(Wih, NH,  64 + jrow, 0, quad, NLOG2E);
        s16x8 wiz1 = bfragW(Wih, NH,  64 + jrow, 1, quad, NLOG2E);
        s16x8 win0 = bfragW(Wih, NH, 128 + jrow, 0, quad, N2LOG2E);
        s16x8 win1 = bfragW(Wih, NH, 128 + jrow, 1, quad, N2LOG2E);
        s16x8 whr0 = bfragW(Whh, NH,   0 + jrow, 0, quad, NLOG2E);
        s16x8 whr1 = bfragW(Whh, NH,   0 + jrow, 1, quad, NLOG2E);
        s16x8 whz0 = bfragW(Whh, NH,  64 + jrow, 0, quad, NLOG2E);
        s16x8 whz1 = bfragW(Whh, NH,  64 + jrow, 1, quad, NLOG2E);
        s16x8 whn0 = bfragW(Whh, NH, 128 + jrow, 0, quad, N2LOG2E);
        s16x8 whn1 = bfragW(Whh, NH, 128 + jrow, 1, quad, N2LOG2E);
        f32x4 initR, initZ;
        {
            f32x4 a = bias4s(&bih[jq], NLOG2E), b = bias4s(&bhh[jq], NLOG2E);
            initR = a + b;
            f32x4 c = bias4s(&bih[64 + jq], NLOG2E), d = bias4s(&bhh[64 + jq], NLOG2E);
            initZ = c + d;
        }
        const f32x4 initN1 = bias4s(&bih[128 + jq], N2LOG2E);
        const f32x4 initN2 = bias4s(&bhh[128 + jq], N2LOG2E);

        const f32x2 c_one  = { 1.0f,  1.0f};
        const f32x2 c_neg1 = {-1.0f, -1.0f};

        // prologue: gh accumulators for t=0 from h(0)
        f32x4 accR, accZ, accN2;
        {
            s16x8 ha0 = *(const s16x8*)&Hs[0][dir][0][quad][n][0];
            s16x8 ha1 = *(const s16x8*)&Hs[0][dir][1][quad][n][0];
            accR  = MFMA(whr0, ha0, initR);  accR  = MFMA(whr1, ha1, accR);
            accZ  = MFMA(whz0, ha0, initZ);  accZ  = MFMA(whz1, ha1, accZ);
            accN2 = MFMA(whn0, ha0, initN2); accN2 = MFMA(whn1, ha1, accN2);
        }

#define GSTEP(HB) do {                                                          \
        __builtin_amdgcn_s_setprio(1);  /* leg1: gates are the straggler */     \
        s16x8 xa0 = *(const s16x8*)&Xs[HB][0][quad][n][0];                      \
        s16x8 xa1 = *(const s16x8*)&Xs[HB][1][quad][n][0];                      \
        /* R23 issue order: accR (heads the eU chain) -> accN1 (needed at */    \
        /* u) -> accZ (tail-only). Per-acc association order unchanged.  */    \
        accR = MFMA(wir0, xa0, accR);   accR = MFMA(wir1, xa1, accR);           \
        f32x4 accN1 = MFMA(win0, xa0, initN1);                                  \
        accN1 = MFMA(win1, xa1, accN1);                                         \
        accZ = MFMA(wiz0, xa0, accZ);   accZ = MFMA(wiz1, xa1, accZ);           \
        /* scale-folded merged-rcp GRU update (rounding-identical): */          \
        f32x4 eR = v_exp2(accR);                                                \
        f32x4 rr = v_rcp(pk_addc(eR, c_one));                                   \
        f32x4 u  = pk_fma(rr, accN2, accN1);                                    \
        f32x4 eU = v_exp2(u);                                                   \
        f32x4 eZ = v_exp2(accZ);                                                \
        f32x4 t1 = pk_add(eZ, hreg);                                            \
        f32x4 t2 = pk_fmac(eZ, c_neg1, hreg);   /* hreg - eZ */                 \
        f32x4 numer = pk_fma(eU, t2, t1);                                       \
        f32x4 tz    = pk_addc(eZ, c_one);                                       \
        f32x4 denom = pk_fma(eU, tz, tz);       /* (eU+1)(eZ+1) via fma */      \
        hreg = pk_mul(numer, v_rcp(denom));                                     \
        *(int2*)&Hs[(HB) ^ 1][dir][wfrag][wq][n][we] = pk4bf(hreg);             \
        __builtin_amdgcn_s_setprio(0);  /* leg2: yield to latent waves */       \
        __syncthreads();  /* b1: H(t+1) visible */                              \
        {                                                                       \
            s16x8 ha0 = *(const s16x8*)&Hs[(HB) ^ 1][dir][0][quad][n][0];       \
            s16x8 ha1 = *(const s16x8*)&Hs[(HB) ^ 1][dir][1][quad][n][0];       \
            accR  = MFMA(whr0, ha0, initR);  accR  = MFMA(whr1, ha1, accR);     \
            accZ  = MFMA(whz0, ha0, initZ);  accZ  = MFMA(whz1, ha1, accZ);     \
            accN2 = MFMA(whn0, ha0, initN2); accN2 = MFMA(whn1, ha1, accN2);    \
        }                                                                       \
        __syncthreads();  /* b2: x(t+1) visible */                              \
    } while (0)

        for (int t = 0; t < NS; t += 2) {
            GSTEP(0);
            GSTEP(1);
        }
#undef GSTEP
    } else {
        // =============== LATENT WAVES (+ fused OUT-PROJ on lt<2) ===============
        const int lt = wave & 3;
        s16x8 wl0 = bfragW(Wlat, 2 * NH, lt * 16 + n, 0, quad, 1.0f);
        s16x8 wl1 = bfragW(Wlat, 2 * NH, lt * 16 + n, 1, quad, 1.0f);
        s16x8 wl2 = bfragW(Wlat, 2 * NH, lt * 16 + n, 2, quad, 1.0f);
        s16x8 wl3 = bfragW(Wlat, 2 * NH, lt * 16 + n, 3, quad, 1.0f);
        const f32x4 initL = bias4s(&blat[lt * 16 + quad * 4], 1.0f);
        // Xs/X2s write-slot coords for this wave's 4 latent cols
        const int lfrag = lt >> 1;
        const int lq    = ((lt & 1) << 1) | (quad >> 1);
        const int le    = (quad & 1) << 2;

        const f32x2 c_lk  = {1e-2f, 1e-2f};
        const f32x2 c_lk2 = {1e-4f, 1e-4f};

        // out-proj state (waves 8-9 only: f-tile f0 = lt*16), pre-scaled -log2e
        s16x8 wo0 = {}, wo1 = {};
        f32x4 initO = {0.f, 0.f, 0.f, 0.f};
        float* orow = nullptr;
        if (lt < 2) {
            const int f0 = lt * 16;
            wo0   = bfragW(Wout, NH, f0 + n, 0, quad, NLOG2E);
            wo1   = bfragW(Wout, NH, f0 + n, 1, quad, NLOG2E);
            initO = bias4s(&bout[f0 + quad * 4], NLOG2E);
            orow  = out + (size_t)(row0 + n) * (NS * NF) + f0 + quad * 4;
        }
        const f32x4 zero4 = {0.f, 0.f, 0.f, 0.f};

#define LOSTEP(HB, T) do {                                                      \
        if (lt < 2 && (T) > 0) {                                                \
            /* leg1 (prio 0 — slack, must stay SHORT): out-proj of y(T-1) */    \
            /* from X2s[HB]; store never drained (raw barriers).          */    \
            s16x8 p0 = *(const s16x8*)&X2s[HB][0][quad][n][0];                  \
            s16x8 p1 = *(const s16x8*)&X2s[HB][1][quad][n][0];                  \
            f32x4 po = MFMA(wo0, p0, initO);                                    \
            po = MFMA(wo1, p1, po);                                             \
            *(f32x4*)(orow + (size_t)((T) - 1) * NF) = v_sigm_pre(po);          \
        }                                                                       \
        bar_nodrain();    /* b1: H(T+1) visible (we have nothing pending) */    \
        __builtin_amdgcn_s_setprio(1);  /* leg2: latent is the straggler */     \
        s16x8 fa0 = *(const s16x8*)&Hs[(HB) ^ 1][0][0][quad][n][0];             \
        s16x8 fa1 = *(const s16x8*)&Hs[(HB) ^ 1][0][1][quad][n][0];             \
        s16x8 ba0 = *(const s16x8*)&Hs[(HB) ^ 1][1][0][quad][n][0];             \
        s16x8 ba1 = *(const s16x8*)&Hs[(HB) ^ 1][1][1][quad][n][0];             \
        f32x4 lac1 = MFMA(wl0, fa0, initL);                                     \
        lac1 = MFMA(wl1, fa1, lac1);                                            \
        f32x4 lac2 = MFMA(wl2, ba0, zero4);                                     \
        lac2 = MFMA(wl3, ba1, lac2);                                            \
        f32x4 la = pk_add(lac1, lac2);                                          \
        *(int2*)&Xs[(HB) ^ 1][lfrag][lq][n][le]  = pk4bf(pk_lk(la, c_lk));      \
        *(int2*)&X2s[(HB) ^ 1][lfrag][lq][n][le] = pk4bf(pk_lk(la, c_lk2));     \
        __builtin_amdgcn_s_setprio(0);  /* leg1: yield to gate waves */         \
        bar_lgkm();       /* b2: x(T+1) visible (lgkm drain only) */            \
    } while (0)

        for (int t = 0; t < NS; t += 2) {
            LOSTEP(0, t);
            LOSTEP(1, t + 1);
        }
#undef LOSTEP

        // epilogue: y(NS-1) from X2s[0] (= lk2(x(NS)), written at T=NS-1,
        // visible via the loop's final bar_lgkm)
        if (lt < 2) {
            s16x8 p0 = *(const s16x8*)&X2s[0][0][quad][n][0];
            s16x8 p1 = *(const s16x8*)&X2s[0][1][quad][n][0];
            f32x4 po = MFMA(wo0, p0, initO);
            po = MFMA(wo1, p1, po);
            *(f32x4*)(orow + (size_t)(NS - 1) * NF) = v_sigm_pre(po);
        }
    }
}

extern "C" void kernel_launch(void* const* d_in, const int* in_sizes, int n_in,
                              void* d_out, int out_size, void* d_ws, size_t ws_size,
                              hipStream_t stream) {
    const float* noise = (const float*)d_in[0];
    const float* Wihf  = (const float*)d_in[1];
    const float* Whhf  = (const float*)d_in[2];
    const float* bihf  = (const float*)d_in[3];
    const float* bhhf  = (const float*)d_in[4];
    const float* Wihb  = (const float*)d_in[5];
    const float* Whhb  = (const float*)d_in[6];
    const float* bihb  = (const float*)d_in[7];
    const float* bhhb  = (const float*)d_in[8];
    const float* Wlat  = (const float*)d_in[9];
    const float* blat  = (const float*)d_in[10];
    const float* Wout  = (const float*)d_in[11];
    const float* bout  = (const float*)d_in[12];

    grugan_kernel<<<dim3(NBATCH / MROW), dim3(768), 0, stream>>>(
        noise, Wihf, Whhf, bihf, bhhf, Wihb, Whhb, bihb, bhhb,
        Wlat, blat, Wout, bout, (float*)d_out);
}